// Round 5
// baseline (126.795 us; speedup 1.0000x reference)
//
#include <hip/hip_runtime.h>
#include <stdint.h>

typedef __bf16 bf16x8 __attribute__((ext_vector_type(8)));
typedef float f32x4 __attribute__((ext_vector_type(4)));

#define N_ROWS 4096
#define KD 128
#define BM 128                    // I-tile rows; each bfrag ds_read feeds 2 MFMAs
#define CHUNK 128                 // B-chunk rows per LDS stage
#define NCHUNK 32
#define NITILE 32
#define NBLOCKS (NITILE * NCHUNK) // 1024 blocks = 32 itiles x 32 chunks

// ctrl layout (zeroed by ONE tiny hipMemsetAsync):
// [0..31] per-itile tickets, [32] root ticket, [33] gsum (f32 0.0), [34] gcnt
#define CTRL_WORDS 35

__device__ __forceinline__ unsigned short f32_to_bf16_rne(float f) {
    union { float f; uint32_t u; } v; v.f = f;
    uint32_t u = v.u;
    return (unsigned short)((u + 0x7FFFu + ((u >> 16) & 1u)) >> 16);
}

// XOR-swizzled LDS index for uint4 units (validated: conflict-free for both
// the dword-per-lane normalize writes and the b128 fragment reads).
__device__ __forceinline__ int swz(int row, int c) { return row * 16 + (c ^ (row & 15)); }

// Wave-per-row normalization into swizzled LDS — BIT-IDENTICAL math to the
// previously validated standalone normalize kernel (same shfl tree, same
// Newton step, same RNE), so all downstream dots are unchanged.
__device__ __forceinline__ void norm_chunk_to_lds(const float* __restrict__ E,
                                                  unsigned* lds, int gbase,
                                                  int wave, int lane) {
#pragma unroll 4
    for (int rr = 0; rr < 32; ++rr) {
        const int r = wave * 32 + rr;                 // chunk-local row
        const float2 v = *(const float2*)&E[(size_t)(gbase + r) * KD + lane * 2];
        float s = v.x * v.x + v.y * v.y;
#pragma unroll
        for (int m = 1; m < 64; m <<= 1) s += __shfl_xor(s, m, 64);
        float inv = 0.0f;
        if (s > 0.0f) {
            inv = rsqrtf(s);
            inv = inv * (1.5f - 0.5f * s * inv * inv);  // Newton: ~1e-7 rel err
        }
        const unsigned short a = f32_to_bf16_rne(v.x * inv);
        const unsigned short b = f32_to_bf16_rne(v.y * inv);
        // lane owns dword `lane` of the row: uint4 c = lane>>2, sub = lane&3
        lds[swz(r, lane >> 2) * 4 + (lane & 3)] = ((unsigned)b << 16) | a;
    }
}

// ---- Single fused kernel: in-LDS normalize -> MFMA gram -> min/max epilogue
// -> agent-scope partial stores -> fence-free 2-level ticket -> per-itile
// aggregation -> root writes the loss. No ebits, no separate dispatches.
__global__ __launch_bounds__(256, 2) void fused_kernel(const float* __restrict__ E,
                                                       const int* __restrict__ labels,
                                                       unsigned long long* __restrict__ partials,
                                                       unsigned* __restrict__ ctrl,
                                                       float* __restrict__ out) {
    // Exactly 64 KiB static LDS: A-tile | B-tile. Post-loop scratch aliases in.
    __shared__ uint4 AB[4096];
    uint4* const As4 = AB;          // 32 KB (A chunk, bf16, swizzled)
    uint4* const Bs4 = AB + 2048;   // 32 KB (B chunk)

    const int tid = threadIdx.x;
    const int itile = blockIdx.x & 31;
    const int chunk = blockIdx.x >> 5;
    const int ibase = itile * BM;
    const int cbase = chunk * CHUNK;
    const int wave = tid >> 6, lane = tid & 63;
    const int quad = lane >> 4, l15 = lane & 15;

    // Label prefetch (registers; labels are L2-hot 16 KB).
    int lj_t[8];
#pragma unroll
    for (int t = 0; t < 8; ++t) lj_t[t] = labels[cbase + t * 16 + l15];
    int li_lab[2][4];
#pragma unroll
    for (int mb = 0; mb < 2; ++mb)
#pragma unroll
        for (int r = 0; r < 4; ++r)
            li_lab[mb][r] = labels[ibase + wave * 32 + mb * 16 + quad * 4 + r];

    // ---- Phase N: normalize the two needed chunks into LDS.
    norm_chunk_to_lds(E, (unsigned*)Bs4, cbase, wave, lane);
    const uint4* aLds = Bs4;
    if (itile != chunk) {                      // diagonal blocks alias A = B
        norm_chunk_to_lds(E, (unsigned*)As4, ibase, wave, lane);
        aLds = As4;
    }
    __syncthreads();

    // ---- Phase G: validated MFMA core (A-frags now from LDS).
    bf16x8 afrag[2][4];
#pragma unroll
    for (int mb = 0; mb < 2; ++mb)
#pragma unroll
        for (int s = 0; s < 4; ++s)
            afrag[mb][s] = *(const bf16x8*)&aLds[swz(wave * 32 + mb * 16 + l15, s * 4 + quad)];

    float minpos[2][4] = {{2.f, 2.f, 2.f, 2.f}, {2.f, 2.f, 2.f, 2.f}};
    float maxneg[2][4] = {{-2.f, -2.f, -2.f, -2.f}, {-2.f, -2.f, -2.f, -2.f}};

#pragma unroll
    for (int t = 0; t < 8; ++t) {
        f32x4 acc0 = {0.f, 0.f, 0.f, 0.f};
        f32x4 acc1 = {0.f, 0.f, 0.f, 0.f};
#pragma unroll
        for (int s = 0; s < 4; ++s) {
            const bf16x8 bfrag = *(const bf16x8*)&Bs4[swz(t * 16 + l15, s * 4 + quad)];
            acc0 = __builtin_amdgcn_mfma_f32_16x16x32_bf16(afrag[0][s], bfrag, acc0, 0, 0, 0);
            acc1 = __builtin_amdgcn_mfma_f32_16x16x32_bf16(afrag[1][s], bfrag, acc1, 0, 0, 0);
        }
        // C/D layout: col = lane&15 (j), row = quad*4 + reg (i)  [m89/m91]
        const int jg = cbase + t * 16 + l15;
        const int lj = lj_t[t];
#pragma unroll
        for (int mb = 0; mb < 2; ++mb) {
            const int ig0 = ibase + wave * 32 + mb * 16 + quad * 4;
#pragma unroll
            for (int r = 0; r < 4; ++r) {
                const float d = (mb == 0) ? acc0[r] : acc1[r];
                const bool same = (lj == li_lab[mb][r]);
                const float dp = (same && (ig0 + r != jg)) ? d : 2.0f;
                const float dn = same ? -2.0f : d;
                minpos[mb][r] = fminf(minpos[mb][r], dp);
                maxneg[mb][r] = fmaxf(maxneg[mb][r], dn);
            }
        }
    }

    // Reduce across the 16 col-lanes of each quad; rows live in (mb,quad,reg).
#pragma unroll
    for (int m = 1; m < 16; m <<= 1) {
#pragma unroll
        for (int mb = 0; mb < 2; ++mb)
#pragma unroll
            for (int r = 0; r < 4; ++r) {
                minpos[mb][r] = fminf(minpos[mb][r], __shfl_xor(minpos[mb][r], m, 64));
                maxneg[mb][r] = fmaxf(maxneg[mb][r], __shfl_xor(maxneg[mb][r], m, 64));
            }
    }

    // ---- Phase P: per-(row,chunk) partials as agent-scope 8B atomic stores
    // (write-through to the coherence point -> visible to the aggregator
    // without any fence; every slot written exactly once, no init needed).
    if (l15 == 0) {
#pragma unroll
        for (int mb = 0; mb < 2; ++mb) {
            const int ig0 = ibase + wave * 32 + mb * 16 + quad * 4;
#pragma unroll
            for (int r = 0; r < 4; ++r) {
                union { float2 f; unsigned long long u; } v;
                v.f = make_float2(minpos[mb][r], maxneg[mb][r]);
                __hip_atomic_store(&partials[(size_t)(ig0 + r) * NCHUNK + chunk], v.u,
                                   __ATOMIC_RELAXED, __HIP_MEMORY_SCOPE_AGENT);
            }
        }
    }

    // ---- Phase T: fence-free two-level ticket. __syncthreads drains each
    // wave's vmcnt (stores retired at coherence point) before tid0's RMW —
    // the exact pattern the validated 72.6µs finalize kernel used.
    __shared__ unsigned s_flag;
    __syncthreads();
    if (tid == 0) {
        const unsigned o = __hip_atomic_fetch_add(&ctrl[itile], 1u,
                                                  __ATOMIC_RELAXED, __HIP_MEMORY_SCOPE_AGENT);
        s_flag = (o == NCHUNK - 1) ? 1u : 0u;
    }
    __syncthreads();
    if (s_flag == 0u) return;

    // ---- Phase A: this block is the LAST of its itile -> aggregate its 128
    // rows across 32 chunks (32 KB of agent-scope loads, 32 itiles parallel).
    float* ssum = (float*)AB;           // LDS dead past here; alias scratch
    int* scnt = (int*)AB + 4;
    const int row_l = tid >> 1;         // 0..127
    const int half = tid & 1;           // 16 chunks each
    const size_t prow = (size_t)(ibase + row_l) * NCHUNK;
    float mp = 2.f, mn = -2.f;
#pragma unroll
    for (int k = 0; k < 16; ++k) {
        union { float2 f; unsigned long long u; } v;
        v.u = __hip_atomic_load(&partials[prow + half * 16 + k],
                                __ATOMIC_RELAXED, __HIP_MEMORY_SCOPE_AGENT);
        mp = fminf(mp, v.f.x);
        mn = fmaxf(mn, v.f.y);
    }
    mp = fminf(mp, __shfl_xor(mp, 1, 64));
    mn = fmaxf(mn, __shfl_xor(mn, 1, 64));

    float sum = 0.f; int cnt = 0;
    if (half == 0 && mp < 1.5f && mn > -1.5f) {  // valid: >=1 pos and >=1 neg
        sum = fmaxf(0.f, mn - mp + 0.3f);        // relu(hp_dist - hn_dist + margin)
        cnt = 1;
    }
#pragma unroll
    for (int m = 1; m < 64; m <<= 1) {
        sum += __shfl_xor(sum, m, 64);
        cnt += __shfl_xor(cnt, m, 64);
    }
    if (lane == 0) { ssum[wave] = sum; scnt[wave] = cnt; }
    __syncthreads();
    if (tid == 0) {
        atomicAdd((float*)&ctrl[33], ssum[0] + ssum[1] + ssum[2] + ssum[3]);
        atomicAdd(&ctrl[34], (unsigned)(scnt[0] + scnt[1] + scnt[2] + scnt[3]));
        asm volatile("s_waitcnt vmcnt(0)" ::: "memory");  // adds durable before root RMW
        const unsigned o2 = __hip_atomic_fetch_add(&ctrl[32], 1u,
                                                   __ATOMIC_RELAXED, __HIP_MEMORY_SCOPE_AGENT);
        s_flag = (o2 == NITILE - 1) ? 2u : 0u;
    }
    __syncthreads();
    if (s_flag == 2u && tid == 0) {
        const float S = __hip_atomic_load((float*)&ctrl[33],
                                          __ATOMIC_RELAXED, __HIP_MEMORY_SCOPE_AGENT);
        const unsigned C = __hip_atomic_load(&ctrl[34],
                                             __ATOMIC_RELAXED, __HIP_MEMORY_SCOPE_AGENT);
        out[0] = S / (float)(C > 0u ? C : 1u);
    }
}

extern "C" void kernel_launch(void* const* d_in, const int* in_sizes, int n_in,
                              void* d_out, int out_size, void* d_ws, size_t ws_size,
                              hipStream_t stream) {
    const float* E = (const float*)d_in[0];
    const int* labels = (const int*)d_in[1];

    unsigned long long* partials = (unsigned long long*)d_ws;        // 1 MiB
    unsigned* ctrl = (unsigned*)((char*)d_ws + (size_t)N_ROWS * NCHUNK * 8);
    float* out = (float*)d_out;

    hipMemsetAsync(ctrl, 0, CTRL_WORDS * sizeof(unsigned), stream);  // tickets+gsum+gcnt
    fused_kernel<<<NBLOCKS, 256, 0, stream>>>(E, labels, partials, ctrl, out);
}

// Round 8
// 72.871 us; speedup vs baseline: 1.7400x; 1.7400x over previous
//
#include <hip/hip_runtime.h>
#include <stdint.h>

typedef __bf16 bf16x8 __attribute__((ext_vector_type(8)));
typedef float f32x4 __attribute__((ext_vector_type(4)));

#define N_ROWS 4096
#define KD 128
#define BM 128                    // I-tile rows: each bfrag ds_read feeds 2 MFMAs
#define NCHUNK 32
#define CHUNK 128                 // whole chunk staged once; ONE barrier per block
#define NITILE 32
#define NBLOCKS (NITILE * NCHUNK) // 1024 blocks = 32 I-tiles x 32 chunks = exactly 4/CU

// ctrl layout (zeroed by normalize block 0):
// [0..31] per-itile tickets, [32] root ticket, [33] gsum (f32), [34] gcnt
#define CTRL_WORDS 35

__device__ __forceinline__ unsigned short f32_to_bf16_rne(float f) {
    union { float f; uint32_t u; } v; v.f = f;
    uint32_t u = v.u;
    return (unsigned short)((u + 0x7FFFu + ((u >> 16) & 1u)) >> 16);
}

// XOR-swizzled LDS index for uint4 units: (row, kblock c) -> row*16 + (c ^ (row&15)).
// Involution within each 16-uint4 row: used BOTH as the read swizzle and as the
// inverse-source permutation for linear-dest global_load_lds (rule-21 pattern).
__device__ __forceinline__ int swz(int row, int c) { return row * 16 + (c ^ (row & 15)); }
__device__ __forceinline__ int swzL(int L) { return (L & ~15) | ((L & 15) ^ ((L >> 4) & 15)); }

// ---- Dispatch 1: one wave per row, L2-normalize -> bf16 RNE, pack 2/lane.
// Block 0 zeroes all ctrl words (tickets + gsum + gcnt); kernel-boundary
// release makes them visible to gram (validated pattern, rounds 0-4).
__global__ __launch_bounds__(256) void normalize_kernel(const float* __restrict__ E,
                                                        unsigned short* __restrict__ out,
                                                        unsigned* __restrict__ ctrl) {
    if (blockIdx.x == 0 && threadIdx.x < CTRL_WORDS) ctrl[threadIdx.x] = 0u;
    const int wave = threadIdx.x >> 6;
    const int lane = threadIdx.x & 63;
    const int row = blockIdx.x * 4 + wave;
    const float2 v = *(const float2*)&E[row * KD + lane * 2];
    float s = v.x * v.x + v.y * v.y;
#pragma unroll
    for (int m = 1; m < 64; m <<= 1) s += __shfl_xor(s, m, 64);
    float inv = 0.0f;
    if (s > 0.0f) {
        inv = rsqrtf(s);
        inv = inv * (1.5f - 0.5f * s * inv * inv);  // Newton step: ~1e-7 rel err
    }
    const unsigned short a = f32_to_bf16_rne(v.x * inv);
    const unsigned short b = f32_to_bf16_rne(v.y * inv);
    ((uint32_t*)out)[row * (KD / 2) + lane] = ((uint32_t)b << 16) | a;
}

// ---- Dispatch 2: round-4 gram (BM=128, global_load_lds staging, 4 blocks/CU)
// with the round-5-validated fence-free tail: agent-scope 8B atomic partial
// stores -> per-itile ticket (32 arrivals, plain device-scope atomicAdd, the
// exact R0-proven primitive) -> 32 parallel aggregators -> root ticket ->
// loss. No finalize dispatch, no threadfence, no spin-waits.
__global__ __launch_bounds__(256, 4) void gram_kernel(const unsigned short* __restrict__ Ebits,
                                                      const int* __restrict__ labels,
                                                      unsigned long long* __restrict__ partials,
                                                      unsigned* __restrict__ ctrl,
                                                      float* __restrict__ out) {
    __shared__ uint4 Bs4[CHUNK * (KD / 8)];  // 32 KB
    __shared__ int ljs[CHUNK];               // 512 B
    __shared__ unsigned s_flag;
    __shared__ float ssum[4];
    __shared__ int scnt[4];

    const int tid = threadIdx.x;
    const int itile = blockIdx.x & 31;
    const int chunk = blockIdx.x >> 5;
    const int ibase = itile * BM;
    const int cbase = chunk * CHUNK;

    const int wave = tid >> 6, lane = tid & 63;
    const int quad = lane >> 4, l15 = lane & 15;

    // Async-stage whole B-chunk: 8 x global_load_lds_dwordx4 per thread-slot.
    // LDS dest linear (wave-uniform base + lane*16); global source pre-swizzled
    // with the same involution the reads use.
    {
        const uint4* src = (const uint4*)(Ebits + (size_t)cbase * KD);
#pragma unroll
        for (int it = 0; it < 8; ++it) {
            const int Ld = it * 256 + wave * 64 + lane;  // linear dest slot
            const int Ls = swzL(Ld);                     // inverse-swizzled source
            __builtin_amdgcn_global_load_lds(
                (const __attribute__((address_space(1))) void*)&src[Ls],
                (__attribute__((address_space(3))) void*)&Bs4[it * 256 + wave * 64],
                16, 0, 0);
        }
    }
    if (tid < CHUNK) ljs[tid] = labels[cbase + tid];

    // A fragments for the wave's two m-blocks: A[m=l15][k = s*32 + quad*8 ..+7].
    bf16x8 afrag[2][4];
    {
        const uint4* asrc = (const uint4*)Ebits;
#pragma unroll
        for (int mb = 0; mb < 2; ++mb) {
            const int arow = ibase + wave * 32 + mb * 16 + l15;
#pragma unroll
            for (int s = 0; s < 4; ++s)
                afrag[mb][s] = *(const bf16x8*)&asrc[arow * 16 + s * 4 + quad];
        }
    }
    int li_lab[2][4];
#pragma unroll
    for (int mb = 0; mb < 2; ++mb)
#pragma unroll
        for (int r = 0; r < 4; ++r)
            li_lab[mb][r] = labels[ibase + wave * 32 + mb * 16 + quad * 4 + r];

    __syncthreads();  // drains gload_lds vmcnt + ds writes

    float minpos[2][4] = {{2.f, 2.f, 2.f, 2.f}, {2.f, 2.f, 2.f, 2.f}};
    float maxneg[2][4] = {{-2.f, -2.f, -2.f, -2.f}, {-2.f, -2.f, -2.f, -2.f}};

    // Pure ds_read + MFMA + epilogue stream: 8 j-tiles, no barriers.
#pragma unroll
    for (int t = 0; t < 8; ++t) {
        f32x4 acc0 = {0.f, 0.f, 0.f, 0.f};
        f32x4 acc1 = {0.f, 0.f, 0.f, 0.f};
#pragma unroll
        for (int s = 0; s < 4; ++s) {
            const bf16x8 bfrag = *(const bf16x8*)&Bs4[swz(t * 16 + l15, s * 4 + quad)];
            acc0 = __builtin_amdgcn_mfma_f32_16x16x32_bf16(afrag[0][s], bfrag, acc0, 0, 0, 0);
            acc1 = __builtin_amdgcn_mfma_f32_16x16x32_bf16(afrag[1][s], bfrag, acc1, 0, 0, 0);
        }
        // C/D layout: col = lane&15 (j), row = quad*4 + reg (i)  [m89/m91]
        const int jg = cbase + t * 16 + l15;
        const int lj = ljs[t * 16 + l15];
#pragma unroll
        for (int mb = 0; mb < 2; ++mb) {
            const int ig0 = ibase + wave * 32 + mb * 16 + quad * 4;
#pragma unroll
            for (int r = 0; r < 4; ++r) {
                const float d = (mb == 0) ? acc0[r] : acc1[r];
                const bool same = (lj == li_lab[mb][r]);
                const float dp = (same && (ig0 + r != jg)) ? d : 2.0f;
                const float dn = same ? -2.0f : d;
                minpos[mb][r] = fminf(minpos[mb][r], dp);
                maxneg[mb][r] = fmaxf(maxneg[mb][r], dn);
            }
        }
    }

    // Reduce across the 16 col-lanes of each quad; rows live in (mb,quad,reg).
#pragma unroll
    for (int m = 1; m < 16; m <<= 1) {
#pragma unroll
        for (int mb = 0; mb < 2; ++mb)
#pragma unroll
            for (int r = 0; r < 4; ++r) {
                minpos[mb][r] = fminf(minpos[mb][r], __shfl_xor(minpos[mb][r], m, 64));
                maxneg[mb][r] = fmaxf(maxneg[mb][r], __shfl_xor(maxneg[mb][r], m, 64));
            }
    }

    // Per-(row,chunk) partials as agent-scope 8B atomic stores (write-through
    // to the coherence point; visible to aggregators without fences — R5-validated).
    if (l15 == 0) {
#pragma unroll
        for (int mb = 0; mb < 2; ++mb) {
            const int ig0 = ibase + wave * 32 + mb * 16 + quad * 4;
#pragma unroll
            for (int r = 0; r < 4; ++r) {
                union { float2 f; unsigned long long u; } v;
                v.f = make_float2(minpos[mb][r], maxneg[mb][r]);
                __hip_atomic_store(&partials[(size_t)(ig0 + r) * NCHUNK + chunk], v.u,
                                   __ATOMIC_RELAXED, __HIP_MEMORY_SCOPE_AGENT);
            }
        }
    }

    // Fence-free per-itile ticket: __syncthreads drains each wave's vmcnt
    // (stores retired at coherence point) before tid0's RMW. Plain atomicAdd
    // = device scope on gfx950 (m20) — the exact R0-proven ticket primitive.
    __syncthreads();
    if (tid == 0) {
        const unsigned o = atomicAdd(&ctrl[itile], 1u);
        s_flag = (o == NCHUNK - 1) ? 1u : 0u;
    }
    __syncthreads();
    if (s_flag == 0u) return;

    // ---- Last block of this itile: aggregate its 128 rows x 32 chunks
    // (32 KB of agent-scope loads; all 32 itile-aggregators run in parallel).
    const int row_l = tid >> 1;         // 0..127
    const int half = tid & 1;           // 16 chunks each
    const size_t prow = (size_t)(ibase + row_l) * NCHUNK;
    float mp = 2.f, mn = -2.f;
#pragma unroll
    for (int k = 0; k < 16; ++k) {
        union { float2 f; unsigned long long u; } v;
        v.u = __hip_atomic_load(&partials[prow + half * 16 + k],
                                __ATOMIC_RELAXED, __HIP_MEMORY_SCOPE_AGENT);
        mp = fminf(mp, v.f.x);
        mn = fmaxf(mn, v.f.y);
    }
    mp = fminf(mp, __shfl_xor(mp, 1, 64));
    mn = fmaxf(mn, __shfl_xor(mn, 1, 64));

    float sum = 0.f; int cnt = 0;
    if (half == 0 && mp < 1.5f && mn > -1.5f) {  // valid: >=1 pos and >=1 neg
        sum = fmaxf(0.f, mn - mp + 0.3f);        // relu(hp_dist - hn_dist + margin)
        cnt = 1;
    }
#pragma unroll
    for (int m = 1; m < 64; m <<= 1) {
        sum += __shfl_xor(sum, m, 64);
        cnt += __shfl_xor(cnt, m, 64);
    }
    if (lane == 0) { ssum[wave] = sum; scnt[wave] = cnt; }
    __syncthreads();
    if (tid == 0) {
        atomicAdd((float*)&ctrl[33], ssum[0] + ssum[1] + ssum[2] + ssum[3]);
        atomicAdd(&ctrl[34], (unsigned)(scnt[0] + scnt[1] + scnt[2] + scnt[3]));
        __builtin_amdgcn_s_waitcnt(0);  // adds durable (vmcnt 0) before root RMW
        const unsigned o2 = atomicAdd(&ctrl[32], 1u);
        s_flag = (o2 == NITILE - 1) ? 2u : 0u;
    }
    __syncthreads();
    if (s_flag == 2u && tid == 0) {
        const float S = __hip_atomic_load((float*)&ctrl[33],
                                          __ATOMIC_RELAXED, __HIP_MEMORY_SCOPE_AGENT);
        const unsigned C = __hip_atomic_load(&ctrl[34],
                                             __ATOMIC_RELAXED, __HIP_MEMORY_SCOPE_AGENT);
        out[0] = S / (float)(C > 0u ? C : 1u);
    }
}

extern "C" void kernel_launch(void* const* d_in, const int* in_sizes, int n_in,
                              void* d_out, int out_size, void* d_ws, size_t ws_size,
                              hipStream_t stream) {
    const float* E = (const float*)d_in[0];
    const int* labels = (const int*)d_in[1];

    unsigned short* ebits = (unsigned short*)d_ws;                              // 1 MiB
    unsigned long long* partials =
        (unsigned long long*)((char*)d_ws + (size_t)N_ROWS * KD * 2);           // 1 MiB
    unsigned* ctrl = (unsigned*)(partials + (size_t)N_ROWS * NCHUNK);           // 35 words
    float* out = (float*)d_out;

    normalize_kernel<<<N_ROWS / 4, 256, 0, stream>>>(E, ebits, ctrl);
    gram_kernel<<<NBLOCKS, 256, 0, stream>>>(ebits, labels, partials, ctrl, out);
}